// Round 8
// baseline (196.714 us; speedup 1.0000x reference)
//
#include <hip/hip_runtime.h>
#include <hip/hip_bf16.h>

#define D_MODEL 768
#define N_HEADS 12
#define D_HEADK 64
#define BB 2
#define TT 2048
#define M_TOK (BB*TT)          // 4096
#define N_QKV (3*D_MODEL)      // 2304
#define MS_SEG (BB*N_HEADS*TT) // 49152 rows per seg

using f32x4  = __attribute__((ext_vector_type(4))) float;
using f32x16 = __attribute__((ext_vector_type(16))) float;
using s16x8  = __attribute__((ext_vector_type(8))) short;

typedef __attribute__((address_space(1))) const unsigned int ga_u32;
typedef __attribute__((address_space(3))) unsigned int ls_u32;

__device__ __forceinline__ float fast_exp2(float x) {
    return __builtin_amdgcn_exp2f(x);
}

__device__ __forceinline__ unsigned short f2bf(float f) {
    union { float f; unsigned u; } v; v.f = f;
    unsigned r = v.u + 0x7FFFu + ((v.u >> 16) & 1u);
    return (unsigned short)(r >> 16);
}

__device__ __forceinline__ float bf2f(unsigned short u) {
    union { unsigned u; float f; } v; v.u = ((unsigned)u) << 16; return v.f;
}

__device__ __forceinline__ unsigned cvtpk_bf16(float lo, float hi) {
    unsigned d;
    asm("v_cvt_pk_bf16_f32 %0, %1, %2" : "=v"(d) : "v"(lo), "v"(hi));
    return d;
}

// ---------------- X fp32 -> bf16 prepass ------------------------------------
__global__ void xbf_kernel(const float* __restrict__ X, unsigned short* __restrict__ Xb) {
    int idx = (blockIdx.x * 256 + threadIdx.x) * 8;
    float4 v0 = *(const float4*)&X[idx];
    float4 v1 = *(const float4*)&X[idx + 4];
    ushort4 u0, u1;
    u0.x = f2bf(v0.x); u0.y = f2bf(v0.y); u0.z = f2bf(v0.z); u0.w = f2bf(v0.w);
    u1.x = f2bf(v1.x); u1.y = f2bf(v1.y); u1.z = f2bf(v1.z); u1.w = f2bf(v1.w);
    *(ushort4*)&Xb[idx]     = u0;
    *(ushort4*)&Xb[idx + 4] = u1;
}

// ---------------- weight transpose: W [K][N] fp32 -> Wt [N][K] bf16 ----------
__global__ void wtrans_kernel(const float* __restrict__ Wa, const float* __restrict__ Wp,
                              unsigned short* __restrict__ Wta, unsigned short* __restrict__ Wtp) {
    const float* W; unsigned short* Wt; int N;
    if (blockIdx.z == 0) { W = Wa; Wt = Wta; N = N_QKV; }
    else                 { W = Wp; Wt = Wtp; N = D_MODEL; }
    int bx = blockIdx.x * 32;  // n
    if (bx >= N) return;
    int by = blockIdx.y * 32;  // k
    __shared__ float tile[32][33];
    int tx = threadIdx.x & 31;
    int ty = threadIdx.x >> 5;   // 0..7
    #pragma unroll
    for (int i = ty; i < 32; i += 8)
        tile[i][tx] = W[(size_t)(by + i) * N + bx + tx];
    __syncthreads();
    #pragma unroll
    for (int i = ty; i < 32; i += 8)
        Wt[(size_t)(bx + i) * D_MODEL + by + tx] = f2bf(tile[tx][i]);
}

// ---------------- QKV GEMM (m97-style): global_load_lds w16, BK=64 ----------
// Linear LDS [128][64]; bank-conflict fix via source pre-swizzle: 16B slot
// s_phys at (row, s) holds logical slot s^(row&7); frag reads apply same XOR.
__launch_bounds__(256)
__global__ void qkv_kernel(const unsigned short* __restrict__ Xb, const unsigned short* __restrict__ Wt,
                           const float* __restrict__ bias,
                           unsigned short* __restrict__ Qw, unsigned short* __restrict__ Kw,
                           unsigned short* __restrict__ Vw) {
    __shared__ unsigned short As[128*64];
    __shared__ unsigned short Bs[128*64];
    const int m0 = blockIdx.y * 128;
    const int n0 = blockIdx.x * 128;
    const int tid = threadIdx.x;
    const int l  = tid & 63;
    const int w  = tid >> 6;
    const int wr = w >> 1, wc = w & 1;
    const int lr = l & 15, lk4 = l >> 4, li = (l >> 4) * 4;
    const int grw  = l >> 3;            // staging: row within 8-row group
    const int gslt = l & 7;             // staging: physical 16B slot

    f32x4 acc[4][4] = {};
    for (int kt = 0; kt < D_MODEL; kt += 64) {
        #pragma unroll
        for (int i = 0; i < 4; ++i) {
            const int row  = w*32 + i*8 + grw;
            const int gcol = (gslt ^ (row & 7)) << 3;      // pre-swizzled source
            __builtin_amdgcn_global_load_lds(
                (ga_u32*)&Xb[(size_t)(m0 + row) * D_MODEL + kt + gcol],
                (ls_u32*)&As[(w*32 + i*8) * 64], 16, 0, 0);
            __builtin_amdgcn_global_load_lds(
                (ga_u32*)&Wt[(size_t)(n0 + row) * D_MODEL + kt + gcol],
                (ls_u32*)&Bs[(w*32 + i*8) * 64], 16, 0, 0);
        }
        __syncthreads();
        #pragma unroll
        for (int ks = 0; ks < 2; ++ks) {
            s16x8 a[4], bf[4];
            #pragma unroll
            for (int mi = 0; mi < 4; ++mi) {
                const int row = wr*64 + mi*16 + lr;
                const int slot = (ks*4 + lk4) ^ (row & 7);
                a[mi] = *(const s16x8*)&As[row*64 + slot*8];
            }
            #pragma unroll
            for (int ni = 0; ni < 4; ++ni) {
                const int row = wc*64 + ni*16 + lr;
                const int slot = (ks*4 + lk4) ^ (row & 7);
                bf[ni] = *(const s16x8*)&Bs[row*64 + slot*8];
            }
            #pragma unroll
            for (int mi = 0; mi < 4; ++mi)
                #pragma unroll
                for (int ni = 0; ni < 4; ++ni)
                    acc[mi][ni] = __builtin_amdgcn_mfma_f32_16x16x32_bf16(a[mi], bf[ni], acc[mi][ni], 0, 0, 0);
        }
        __syncthreads();
    }
    // epilogue: scatter to Q (pre-scaled by 1/8 * log2e), K, V  (all row-major)
    #pragma unroll
    for (int ni = 0; ni < 4; ++ni) {
        int ng = n0 + wc*64 + ni*16 + lr;
        int mat = ng / D_MODEL;       // uniform per block (128 | 768)
        int hd  = ng % D_MODEL;
        int h = hd >> 6, d = hd & 63;
        float bv = bias[ng];
        #pragma unroll
        for (int mi = 0; mi < 4; ++mi) {
            #pragma unroll
            for (int i = 0; i < 4; ++i) {
                int t  = m0 + wr*64 + mi*16 + li + i;
                int b  = t >> 11, tq = t & 2047;
                float val = acc[mi][ni][i] + bv;
                size_t off = ((size_t)(b*N_HEADS + h)*TT + tq)*64 + d;
                if (mat == 0)      Qw[off] = f2bf(val * 0.18033688f);
                else if (mat == 1) Kw[off] = f2bf(val);
                else               Vw[off] = f2bf(val);
            }
        }
    }
}

// ---------------- V transpose: Vw[bh][t][64] -> Vt[bh][64][t] ---------------
__launch_bounds__(256)
__global__ void vtrans_kernel(const unsigned short* __restrict__ Vw, unsigned short* __restrict__ Vt) {
    __shared__ unsigned short tile[64][65];
    const int bh = blockIdx.y;
    const int t0 = blockIdx.x * 64;
    const int tid = threadIdx.x;
    const int srow = tid >> 3;          // 0..31
    const int scol = (tid & 7) * 8;     // 0..56
    const unsigned short* src = Vw + (size_t)bh * TT * 64;
    unsigned short* dst = Vt + (size_t)bh * 64 * TT;
    *(int4*)&tile[srow][scol]    = *(const int4*)&src[(size_t)(t0 + srow) * 64 + scol];
    *(int4*)&tile[srow+32][scol] = *(const int4*)&src[(size_t)(t0 + srow + 32) * 64 + scol];
    __syncthreads();
    s16x8 a0, a1;
    #pragma unroll
    for (int j = 0; j < 8; ++j) {
        a0[j] = (short)tile[scol + j][srow];
        a1[j] = (short)tile[scol + j][srow + 32];
    }
    *(s16x8*)&dst[(size_t)srow * TT + t0 + scol]        = a0;
    *(s16x8*)&dst[(size_t)(srow + 32) * TT + t0 + scol] = a1;
}

// ---------------- causal flash attention, SPLIT-K (4 segments) --------------
// r5 proven core: 4 waves x 32 q-rows (128-q chunk), 64-k LDS tiles, swapped
// QK^T 32x32 MFMA, lane-local softmax, in-register P via cvt_pk+permlane.
// Chunk qci has ntiles=2(qci+1) k-tiles, split [seg*nt/4,(seg+1)*nt/4) over 4
// blocks; unnormalized bf16 partials + f32 m/s merged by merge_kernel.
__device__ __forceinline__ int swz(int r, int c) { return r*64 + (c ^ ((r & 7) << 3)); }

__launch_bounds__(256)
__global__ void attn_kernel(const unsigned short* __restrict__ Q,
                            const unsigned short* __restrict__ Kk,
                            const unsigned short* __restrict__ Vt,
                            unsigned short* __restrict__ oA,
                            unsigned short* __restrict__ oB,
                            unsigned short* __restrict__ oC,
                            unsigned short* __restrict__ oD,
                            float* __restrict__ ms) {
    __shared__ unsigned short Ks[64*64];
    __shared__ unsigned short Vs[64*64];
    const int bh = blockIdx.y;          // 0..23
    const int px = blockIdx.x;          // 0..63
    const int qci = 15 - (px >> 2);     // longest chunks first
    const int seg = px & 3;
    const int q0 = qci * 128;
    const int b = bh / N_HEADS, h = bh % N_HEADS;
    const int tid = threadIdx.x;
    const int l  = tid & 63;
    const int w  = tid >> 6;            // wave 0..3
    const int lq = l & 31;
    const int hi = l >> 5;
    const int srow = tid >> 3;          // 0..31 (staging)
    const int scol = (tid & 7) * 8;     // 0..56
    const int qw0 = q0 + w * 32;        // this wave's first q-row

    const unsigned short* Qp = Q  + (size_t)bh * TT * 64;
    const unsigned short* Kp = Kk + (size_t)bh * TT * 64;
    const unsigned short* Vp = Vt + (size_t)bh * 64 * TT;

    // k-tile range for this segment (balanced quarters; may be empty)
    const int ntiles  = 2 * (qci + 1);
    const int t_begin = (seg * ntiles) >> 2;
    const int t_end   = ((seg + 1) * ntiles) >> 2;

    // Q fragments (pre-selected by hi so indexing is compile-time)
    s16x8 qsel[4];
    {
        const unsigned short* qrow = &Qp[(size_t)(qw0 + lq) * 64];
        #pragma unroll
        for (int t = 0; t < 4; ++t) {
            s16x8 qlo = *(const s16x8*)&qrow[16*t];
            s16x8 qhi = *(const s16x8*)&qrow[16*t + 8];
            qsel[t] = hi ? qhi : qlo;
        }
    }

    float mi = -1e30f, si = 0.f;
    f32x16 o0 = {}, o1 = {};

    // prefetch first tile of the segment (in-bounds even if segment empty)
    const int kb0 = t_begin * 64;
    int4 kp0 = *(const int4*)&Kp[(size_t)(kb0 + srow) * 64 + scol];
    int4 kp1 = *(const int4*)&Kp[(size_t)(kb0 + srow + 32) * 64 + scol];
    int4 vp0 = *(const int4*)&Vp[(size_t)srow * TT + kb0 + scol];
    int4 vp1 = *(const int4*)&Vp[(size_t)(srow + 32) * TT + kb0 + scol];

    for (int it = t_begin; it < t_end; ++it) {
        const int kt = it * 64;
        __syncthreads();                       // prev compute done, LDS free
        *(int4*)&Ks[swz(srow,      scol)] = kp0;
        *(int4*)&Ks[swz(srow + 32, scol)] = kp1;
        *(int4*)&Vs[swz(srow,      scol)] = vp0;
        *(int4*)&Vs[swz(srow + 32, scol)] = vp1;
        __syncthreads();                       // tile ready
        if (it + 1 < t_end) {                  // prefetch next (hides latency)
            const int k2 = kt + 64;
            kp0 = *(const int4*)&Kp[(size_t)(k2 + srow) * 64 + scol];
            kp1 = *(const int4*)&Kp[(size_t)(k2 + srow + 32) * 64 + scol];
            vp0 = *(const int4*)&Vp[(size_t)srow * TT + k2 + scol];
            vp1 = *(const int4*)&Vp[(size_t)(srow + 32) * TT + k2 + scol];
        }
        #pragma unroll
        for (int kti = 0; kti < 2; ++kti) {
            const int kk = kt + kti * 32;
            if (kk > qw0) continue;            // wave-uniform: post-diagonal
            const bool diag = (kk == qw0);
            // ---- QK^T (swapped): S^T[k][q]; lane: q=lq, k=(r&3)+8(r>>2)+4hi
            f32x16 s = {};
            #pragma unroll
            for (int t = 0; t < 4; ++t) {
                s16x8 a = *(const s16x8*)&Ks[swz(kti*32 + lq, 16*t + 8*hi)];
                s = __builtin_amdgcn_mfma_f32_32x32x16_bf16(a, qsel[t], s, 0, 0, 0);
            }
            if (diag) {
                #pragma unroll
                for (int r = 0; r < 16; ++r) {
                    const int kloc = (r & 3) + 8*(r >> 2) + 4*hi;
                    if (kloc > lq) s[r] = -1e30f;
                }
            }
            // ---- online softmax, lane-local ----
            float lm = s[0];
            #pragma unroll
            for (int r = 1; r < 16; ++r) lm = fmaxf(lm, s[r]);
            if (!__all(lm <= mi + 11.5f)) {    // rare rescale path
                float pm = fmaxf(lm, __shfl_xor(lm, 32));
                float mn = fmaxf(mi, pm);
                float sf = fast_exp2(mi - mn);
                si *= sf;
                #pragma unroll
                for (int r = 0; r < 16; ++r) {
                    const int qloc = (r & 3) + 8*(r >> 2) + 4*hi;
                    float sfq = __shfl(sf, qloc);
                    o0[r] *= sfq; o1[r] *= sfq;
                }
                mi = mn;
            }
            float e[16];
            float psum = 0.f;
            #pragma unroll
            for (int r = 0; r < 16; ++r) {
                e[r] = fast_exp2(s[r] - mi);
                psum += e[r];
            }
            si += psum;
            // ---- P A-frags in-register + PV ----
            #pragma unroll
            for (int s2 = 0; s2 < 2; ++s2) {
                unsigned c0 = cvtpk_bf16(e[8*s2 + 0], e[8*s2 + 1]);
                unsigned c1 = cvtpk_bf16(e[8*s2 + 2], e[8*s2 + 3]);
                unsigned c2 = cvtpk_bf16(e[8*s2 + 4], e[8*s2 + 5]);
                unsigned c3 = cvtpk_bf16(e[8*s2 + 6], e[8*s2 + 7]);
                asm("v_permlane32_swap_b32 %0, %1" : "+v"(c0), "+v"(c2));
                asm("v_permlane32_swap_b32 %0, %1" : "+v"(c1), "+v"(c3));
                union { unsigned u[4]; s16x8 v; } pa;
                pa.u[0] = c0; pa.u[1] = c1; pa.u[2] = c2; pa.u[3] = c3;
                const int kc = kti*32 + 16*s2 + 8*hi;
                s16x8 vb0 = *(const s16x8*)&Vs[swz(lq,      kc)];
                s16x8 vb1 = *(const s16x8*)&Vs[swz(32 + lq, kc)];
                o0 = __builtin_amdgcn_mfma_f32_32x32x16_bf16(pa.v, vb0, o0, 0, 0, 0);
                o1 = __builtin_amdgcn_mfma_f32_32x32x16_bf16(pa.v, vb1, o1, 0, 0, 0);
            }
        }
    }
    // ---- epilogue: write UNNORMALIZED partial + (m, s) per q-row ----
    float sfull = si + __shfl_xor(si, 32);
    if (hi == 0) {   // one lane per q-row (mi identical across the two halves)
        const int row = bh * TT + qw0 + lq;
        ms[seg*MS_SEG + row]       = mi;
        ms[(4+seg)*MS_SEG + row]   = sfull;
    }
    unsigned short* op = (seg == 0) ? oA : (seg == 1) ? oB : (seg == 2) ? oC : oD;
    #pragma unroll
    for (int r = 0; r < 16; ++r) {
        const int qloc = (r & 3) + 8*(r >> 2) + 4*hi;
        size_t row = (size_t)(b*TT + qw0 + qloc) * D_MODEL + h*64;
        op[row + lq]      = f2bf(o0[r]);
        op[row + 32 + lq] = f2bf(o1[r]);
    }
}

// ---------------- merge: Y = sum_i oI*2^(mI-m) / sum_i sI*2^(mI-m) ----------
__launch_bounds__(256)
__global__ void merge_kernel(const unsigned short* __restrict__ oA,
                             const unsigned short* __restrict__ oB,
                             const unsigned short* __restrict__ oC,
                             const unsigned short* __restrict__ oD,
                             const float* __restrict__ ms,
                             unsigned short* __restrict__ Yw) {
    const int gid = blockIdx.x * 256 + threadIdx.x;
    const int e = gid * 8;                       // element idx, 8 per thread
    const int t = e / D_MODEL;                   // 0..4095
    const int c = e % D_MODEL;
    const int b = t >> 11, q = t & 2047;
    const int h = c >> 6;
    const int row = (b * N_HEADS + h) * TT + q;
    float m0 = ms[row],            m1 = ms[MS_SEG + row];
    float m2 = ms[2*MS_SEG + row], m3 = ms[3*MS_SEG + row];
    float s0 = ms[4*MS_SEG + row], s1 = ms[5*MS_SEG + row];
    float s2 = ms[6*MS_SEG + row], s3 = ms[7*MS_SEG + row];
    float m  = fmaxf(fmaxf(m0, m1), fmaxf(m2, m3));
    float a0 = fast_exp2(m0 - m), a1 = fast_exp2(m1 - m);
    float a2 = fast_exp2(m2 - m), a3 = fast_exp2(m3 - m);
    float inv = 1.f / (s0*a0 + s1*a1 + s2*a2 + s3*a3);
    float w0 = a0*inv, w1 = a1*inv, w2 = a2*inv, w3 = a3*inv;
    s16x8 va = *(const s16x8*)&oA[e];
    s16x8 vb = *(const s16x8*)&oB[e];
    s16x8 vc = *(const s16x8*)&oC[e];
    s16x8 vd = *(const s16x8*)&oD[e];
    s16x8 out;
    #pragma unroll
    for (int j = 0; j < 8; ++j)
        out[j] = (short)f2bf(bf2f((unsigned short)va[j]) * w0 +
                             bf2f((unsigned short)vb[j]) * w1 +
                             bf2f((unsigned short)vc[j]) * w2 +
                             bf2f((unsigned short)vd[j]) * w3);
    *(s16x8*)&Yw[e] = out;
}

// ---------------- proj GEMM: Y[4096,768]bf16 x Wt[768,768]bf16 + b -> fp32 --
__launch_bounds__(256)
__global__ void proj_kernel(const unsigned short* __restrict__ Y, const unsigned short* __restrict__ Wt,
                            const float* __restrict__ bias, float* __restrict__ Out) {
    __shared__ unsigned short As[128][40];
    __shared__ unsigned short Bs[128][40];
    const int m0 = blockIdx.y * 128;
    const int n0 = blockIdx.x * 128;
    const int tid = threadIdx.x;
    const int l  = tid & 63;
    const int w  = tid >> 6;
    const int wr = w >> 1, wc = w & 1;
    const int lr = l & 15, lk = (l >> 4) * 8, li = (l >> 4) * 4;

    f32x4 acc[4][4] = {};
    for (int kt = 0; kt < D_MODEL; kt += 32) {
        #pragma unroll
        for (int p = 0; p < 2; ++p) {
            int ch = tid * 2 + p;
            int r = ch >> 2;
            int c = (ch & 3) * 8;
            *(int4*)&As[r][c] = *(const int4*)&Y[(size_t)(m0 + r) * D_MODEL + kt + c];
            *(int4*)&Bs[r][c] = *(const int4*)&Wt[(size_t)(n0 + r) * D_MODEL + kt + c];
        }
        __syncthreads();
        s16x8 a[4], bf[4];
        #pragma unroll
        for (int mi = 0; mi < 4; ++mi)
            a[mi] = *(const s16x8*)&As[wr*64 + mi*16 + lr][lk];
        #pragma unroll
        for (int ni = 0; ni < 4; ++ni)
            bf[ni] = *(const s16x8*)&Bs[wc*64 + ni*16 + lr][lk];
        #pragma unroll
        for (int mi = 0; mi < 4; ++mi)
            #pragma unroll
            for (int ni = 0; ni < 4; ++ni)
                acc[mi][ni] = __builtin_amdgcn_mfma_f32_16x16x32_bf16(a[mi], bf[ni], acc[mi][ni], 0, 0, 0);
        __syncthreads();
    }
    #pragma unroll
    for (int ni = 0; ni < 4; ++ni) {
        int ng = n0 + wc*64 + ni*16 + lr;
        float bv = bias[ng];
        #pragma unroll
        for (int mj = 0; mj < 4; ++mj)
            #pragma unroll
            for (int i = 0; i < 4; ++i) {
                int t = m0 + wr*64 + mj*16 + li + i;
                Out[(size_t)t*D_MODEL + ng] = acc[mj][ni][i] + bv;
            }
    }
}

extern "C" void kernel_launch(void* const* d_in, const int* in_sizes, int n_in,
                              void* d_out, int out_size, void* d_ws, size_t ws_size,
                              hipStream_t stream) {
    const float* x      = (const float*)d_in[0];
    const float* w_attn = (const float*)d_in[1];
    const float* b_attn = (const float*)d_in[2];
    const float* w_proj = (const float*)d_in[3];
    const float* b_proj = (const float*)d_in[4];
    float* out = (float*)d_out;

    unsigned short* wt_attn = (unsigned short*)d_ws;                       // 2304*768
    unsigned short* wt_proj = wt_attn + (size_t)N_QKV * D_MODEL;           // 768*768
    unsigned short* Qw      = wt_proj + (size_t)D_MODEL * D_MODEL;
    unsigned short* Kw      = Qw + (size_t)M_TOK * D_MODEL;
    unsigned short* Vw      = Kw + (size_t)M_TOK * D_MODEL;
    unsigned short* Yw      = Vw + (size_t)M_TOK * D_MODEL;
    unsigned short* Xb      = Yw + (size_t)M_TOK * D_MODEL;
    unsigned short* oC      = Xb + (size_t)M_TOK * D_MODEL;
    unsigned short* oD      = oC + (size_t)M_TOK * D_MODEL;
    unsigned short* Vtw     = Xb;              // Xb dead after qkv; reuse for V^T
    unsigned short* oA      = Vw;              // Vw dead after vtrans: seg0 partial
    unsigned short* oB      = Yw;              // seg1 partial, merged in place
    float*          msbuf   = (float*)d_ws;    // wt_attn region dead after qkv

    hipLaunchKernelGGL(xbf_kernel, dim3(M_TOK*D_MODEL/2048), dim3(256), 0, stream, x, Xb);
    hipLaunchKernelGGL(wtrans_kernel, dim3(N_QKV/32, D_MODEL/32, 2), dim3(256), 0, stream,
                       w_attn, w_proj, wt_attn, wt_proj);
    hipLaunchKernelGGL(qkv_kernel, dim3(N_QKV/128, M_TOK/128), dim3(256), 0, stream,
                       Xb, wt_attn, b_attn, Qw, Kw, Vw);
    hipLaunchKernelGGL(vtrans_kernel, dim3(TT/64, BB*N_HEADS), dim3(256), 0, stream,
                       Vw, Vtw);
    hipLaunchKernelGGL(attn_kernel, dim3(64, BB*N_HEADS), dim3(256), 0, stream,
                       Qw, Kw, Vtw, oA, oB, oC, oD, msbuf);
    hipLaunchKernelGGL(merge_kernel, dim3(M_TOK*D_MODEL/8/256), dim3(256), 0, stream,
                       oA, oB, oC, oD, msbuf, Yw);
    hipLaunchKernelGGL(proj_kernel, dim3(D_MODEL/128, M_TOK/128), dim3(256), 0, stream,
                       Yw, wt_proj, b_proj, out);
}

// Round 9
// 181.395 us; speedup vs baseline: 1.0845x; 1.0845x over previous
//
#include <hip/hip_runtime.h>
#include <hip/hip_bf16.h>

#define D_MODEL 768
#define N_HEADS 12
#define D_HEADK 64
#define BB 2
#define TT 2048
#define M_TOK (BB*TT)          // 4096
#define N_QKV (3*D_MODEL)      // 2304
#define MS_SEG (BB*N_HEADS*TT) // 49152 rows per seg

using f32x4  = __attribute__((ext_vector_type(4))) float;
using f32x16 = __attribute__((ext_vector_type(16))) float;
using s16x8  = __attribute__((ext_vector_type(8))) short;

typedef __attribute__((address_space(1))) const unsigned int ga_u32;
typedef __attribute__((address_space(3))) unsigned int ls_u32;

__device__ __forceinline__ float fast_exp2(float x) {
    return __builtin_amdgcn_exp2f(x);
}

__device__ __forceinline__ unsigned short f2bf(float f) {
    union { float f; unsigned u; } v; v.f = f;
    unsigned r = v.u + 0x7FFFu + ((v.u >> 16) & 1u);
    return (unsigned short)(r >> 16);
}

__device__ __forceinline__ float bf2f(unsigned short u) {
    union { unsigned u; float f; } v; v.u = ((unsigned)u) << 16; return v.f;
}

__device__ __forceinline__ unsigned cvtpk_bf16(float lo, float hi) {
    unsigned d;
    asm("v_cvt_pk_bf16_f32 %0, %1, %2" : "=v"(d) : "v"(lo), "v"(hi));
    return d;
}

// ---------------- fused prepass: X->bf16  +  both weight transposes ---------
// id < 1536: xbf;  [1536,3264): w_attn trans;  [3264,3840): w_proj trans
__global__ void prep_kernel(const float* __restrict__ X, unsigned short* __restrict__ Xb,
                            const float* __restrict__ Wa, const float* __restrict__ Wp,
                            unsigned short* __restrict__ Wta, unsigned short* __restrict__ Wtp) {
    __shared__ float tile[32][33];
    const int id = blockIdx.x;
    if (id < 1536) {
        int idx = (id * 256 + threadIdx.x) * 8;
        float4 v0 = *(const float4*)&X[idx];
        float4 v1 = *(const float4*)&X[idx + 4];
        ushort4 u0, u1;
        u0.x = f2bf(v0.x); u0.y = f2bf(v0.y); u0.z = f2bf(v0.z); u0.w = f2bf(v0.w);
        u1.x = f2bf(v1.x); u1.y = f2bf(v1.y); u1.z = f2bf(v1.z); u1.w = f2bf(v1.w);
        *(ushort4*)&Xb[idx]     = u0;
        *(ushort4*)&Xb[idx + 4] = u1;
        return;
    }
    const float* W; unsigned short* Wt; int N; int j;
    if (id < 1536 + 72*24) { j = id - 1536;        W = Wa; Wt = Wta; N = N_QKV; }
    else                   { j = id - 1536 - 72*24; W = Wp; Wt = Wtp; N = D_MODEL; }
    const int nb = N / 32;
    const int bx = (j % nb) * 32;
    const int by = (j / nb) * 32;
    const int tx = threadIdx.x & 31;
    const int ty = threadIdx.x >> 5;   // 0..7
    #pragma unroll
    for (int i = ty; i < 32; i += 8)
        tile[i][tx] = W[(size_t)(by + i) * N + bx + tx];
    __syncthreads();
    #pragma unroll
    for (int i = ty; i < 32; i += 8)
        Wt[(size_t)(bx + i) * D_MODEL + by + tx] = f2bf(tile[tx][i]);
}

// ---------------- QKV GEMM (m97-style): global_load_lds w16, BK=64 ----------
__launch_bounds__(256)
__global__ void qkv_kernel(const unsigned short* __restrict__ Xb, const unsigned short* __restrict__ Wt,
                           const float* __restrict__ bias,
                           unsigned short* __restrict__ Qw, unsigned short* __restrict__ Kw,
                           unsigned short* __restrict__ Vw) {
    __shared__ unsigned short As[128*64];
    __shared__ unsigned short Bs[128*64];
    const int m0 = blockIdx.y * 128;
    const int n0 = blockIdx.x * 128;
    const int tid = threadIdx.x;
    const int l  = tid & 63;
    const int w  = tid >> 6;
    const int wr = w >> 1, wc = w & 1;
    const int lr = l & 15, lk4 = l >> 4, li = (l >> 4) * 4;
    const int grw  = l >> 3;            // staging: row within 8-row group
    const int gslt = l & 7;             // staging: physical 16B slot

    f32x4 acc[4][4] = {};
    for (int kt = 0; kt < D_MODEL; kt += 64) {
        #pragma unroll
        for (int i = 0; i < 4; ++i) {
            const int row  = w*32 + i*8 + grw;
            const int gcol = (gslt ^ (row & 7)) << 3;      // pre-swizzled source
            __builtin_amdgcn_global_load_lds(
                (ga_u32*)&Xb[(size_t)(m0 + row) * D_MODEL + kt + gcol],
                (ls_u32*)&As[(w*32 + i*8) * 64], 16, 0, 0);
            __builtin_amdgcn_global_load_lds(
                (ga_u32*)&Wt[(size_t)(n0 + row) * D_MODEL + kt + gcol],
                (ls_u32*)&Bs[(w*32 + i*8) * 64], 16, 0, 0);
        }
        __syncthreads();
        #pragma unroll
        for (int ks = 0; ks < 2; ++ks) {
            s16x8 a[4], bf[4];
            #pragma unroll
            for (int mi = 0; mi < 4; ++mi) {
                const int row = wr*64 + mi*16 + lr;
                const int slot = (ks*4 + lk4) ^ (row & 7);
                a[mi] = *(const s16x8*)&As[row*64 + slot*8];
            }
            #pragma unroll
            for (int ni = 0; ni < 4; ++ni) {
                const int row = wc*64 + ni*16 + lr;
                const int slot = (ks*4 + lk4) ^ (row & 7);
                bf[ni] = *(const s16x8*)&Bs[row*64 + slot*8];
            }
            #pragma unroll
            for (int mi = 0; mi < 4; ++mi)
                #pragma unroll
                for (int ni = 0; ni < 4; ++ni)
                    acc[mi][ni] = __builtin_amdgcn_mfma_f32_16x16x32_bf16(a[mi], bf[ni], acc[mi][ni], 0, 0, 0);
        }
        __syncthreads();
    }
    // epilogue: scatter to Q (pre-scaled by 1/8 * log2e), K, V  (all row-major)
    #pragma unroll
    for (int ni = 0; ni < 4; ++ni) {
        int ng = n0 + wc*64 + ni*16 + lr;
        int mat = ng / D_MODEL;       // uniform per block (128 | 768)
        int hd  = ng % D_MODEL;
        int h = hd >> 6, d = hd & 63;
        float bv = bias[ng];
        #pragma unroll
        for (int mi = 0; mi < 4; ++mi) {
            #pragma unroll
            for (int i = 0; i < 4; ++i) {
                int t  = m0 + wr*64 + mi*16 + li + i;
                int b  = t >> 11, tq = t & 2047;
                float val = acc[mi][ni][i] + bv;
                size_t off = ((size_t)(b*N_HEADS + h)*TT + tq)*64 + d;
                if (mat == 0)      Qw[off] = f2bf(val * 0.18033688f);
                else if (mat == 1) Kw[off] = f2bf(val);
                else               Vw[off] = f2bf(val);
            }
        }
    }
}

// ---------------- V transpose: Vw[bh][t][64] -> Vt[bh][64][t] ---------------
__launch_bounds__(256)
__global__ void vtrans_kernel(const unsigned short* __restrict__ Vw, unsigned short* __restrict__ Vt) {
    __shared__ unsigned short tile[64][65];
    const int bh = blockIdx.y;
    const int t0 = blockIdx.x * 64;
    const int tid = threadIdx.x;
    const int srow = tid >> 3;          // 0..31
    const int scol = (tid & 7) * 8;     // 0..56
    const unsigned short* src = Vw + (size_t)bh * TT * 64;
    unsigned short* dst = Vt + (size_t)bh * 64 * TT;
    *(int4*)&tile[srow][scol]    = *(const int4*)&src[(size_t)(t0 + srow) * 64 + scol];
    *(int4*)&tile[srow+32][scol] = *(const int4*)&src[(size_t)(t0 + srow + 32) * 64 + scol];
    __syncthreads();
    s16x8 a0, a1;
    #pragma unroll
    for (int j = 0; j < 8; ++j) {
        a0[j] = (short)tile[scol + j][srow];
        a1[j] = (short)tile[scol + j][srow + 32];
    }
    *(s16x8*)&dst[(size_t)srow * TT + t0 + scol]        = a0;
    *(s16x8*)&dst[(size_t)(srow + 32) * TT + t0 + scol] = a1;
}

// ---------------- causal flash attention, SPLIT-K (4 segs), XCD-pinned ------
// Remap (px,bh) so all blocks of a given bh share blockIdx%8 -> same XCD ->
// its 1.5MB Q/K/V set stays in that XCD's 4MB L2.
__device__ __forceinline__ int swz(int r, int c) { return r*64 + (c ^ ((r & 7) << 3)); }

__launch_bounds__(256)
__global__ void attn_kernel(const unsigned short* __restrict__ Q,
                            const unsigned short* __restrict__ Kk,
                            const unsigned short* __restrict__ Vt,
                            unsigned short* __restrict__ oA,
                            unsigned short* __restrict__ oB,
                            unsigned short* __restrict__ oC,
                            unsigned short* __restrict__ oD,
                            float* __restrict__ ms) {
    __shared__ unsigned short Ks[64*64];
    __shared__ unsigned short Vs[64*64];
    const int f   = blockIdx.y * 64 + blockIdx.x;   // 0..1535
    const int xcd = f & 7;
    const int rr  = f >> 3;                         // 0..191
    const int bh  = xcd * 3 + (rr % 3);             // bh pinned to one XCD
    const int px  = rr / 3;                         // 0..63, ascending = longest first
    const int qci = 15 - (px >> 2);
    const int seg = px & 3;
    const int q0 = qci * 128;
    const int b = bh / N_HEADS, h = bh % N_HEADS;
    const int tid = threadIdx.x;
    const int l  = tid & 63;
    const int w  = tid >> 6;            // wave 0..3
    const int lq = l & 31;
    const int hi = l >> 5;
    const int srow = tid >> 3;          // 0..31 (staging)
    const int scol = (tid & 7) * 8;     // 0..56
    const int qw0 = q0 + w * 32;        // this wave's first q-row

    const unsigned short* Qp = Q  + (size_t)bh * TT * 64;
    const unsigned short* Kp = Kk + (size_t)bh * TT * 64;
    const unsigned short* Vp = Vt + (size_t)bh * 64 * TT;

    // k-tile range for this segment (balanced quarters; may be empty)
    const int ntiles  = 2 * (qci + 1);
    const int t_begin = (seg * ntiles) >> 2;
    const int t_end   = ((seg + 1) * ntiles) >> 2;

    // Q fragments (pre-selected by hi so indexing is compile-time)
    s16x8 qsel[4];
    {
        const unsigned short* qrow = &Qp[(size_t)(qw0 + lq) * 64];
        #pragma unroll
        for (int t = 0; t < 4; ++t) {
            s16x8 qlo = *(const s16x8*)&qrow[16*t];
            s16x8 qhi = *(const s16x8*)&qrow[16*t + 8];
            qsel[t] = hi ? qhi : qlo;
        }
    }

    float mi = -1e30f, si = 0.f;
    f32x16 o0 = {}, o1 = {};

    // prefetch first tile of the segment (in-bounds even if segment empty)
    const int kb0 = t_begin * 64;
    int4 kp0 = *(const int4*)&Kp[(size_t)(kb0 + srow) * 64 + scol];
    int4 kp1 = *(const int4*)&Kp[(size_t)(kb0 + srow + 32) * 64 + scol];
    int4 vp0 = *(const int4*)&Vp[(size_t)srow * TT + kb0 + scol];
    int4 vp1 = *(const int4*)&Vp[(size_t)(srow + 32) * TT + kb0 + scol];

    for (int it = t_begin; it < t_end; ++it) {
        const int kt = it * 64;
        __syncthreads();                       // prev compute done, LDS free
        *(int4*)&Ks[swz(srow,      scol)] = kp0;
        *(int4*)&Ks[swz(srow + 32, scol)] = kp1;
        *(int4*)&Vs[swz(srow,      scol)] = vp0;
        *(int4*)&Vs[swz(srow + 32, scol)] = vp1;
        __syncthreads();                       // tile ready
        if (it + 1 < t_end) {                  // prefetch next (hides latency)
            const int k2 = kt + 64;
            kp0 = *(const int4*)&Kp[(size_t)(k2 + srow) * 64 + scol];
            kp1 = *(const int4*)&Kp[(size_t)(k2 + srow + 32) * 64 + scol];
            vp0 = *(const int4*)&Vp[(size_t)srow * TT + k2 + scol];
            vp1 = *(const int4*)&Vp[(size_t)(srow + 32) * TT + k2 + scol];
        }
        #pragma unroll
        for (int kti = 0; kti < 2; ++kti) {
            const int kk = kt + kti * 32;
            if (kk > qw0) continue;            // wave-uniform: post-diagonal
            const bool diag = (kk == qw0);
            // ---- QK^T (swapped): S^T[k][q]; lane: q=lq, k=(r&3)+8(r>>2)+4hi
            f32x16 s = {};
            __builtin_amdgcn_s_setprio(1);
            #pragma unroll
            for (int t = 0; t < 4; ++t) {
                s16x8 a = *(const s16x8*)&Ks[swz(kti*32 + lq, 16*t + 8*hi)];
                s = __builtin_amdgcn_mfma_f32_32x32x16_bf16(a, qsel[t], s, 0, 0, 0);
            }
            __builtin_amdgcn_s_setprio(0);
            if (diag) {
                #pragma unroll
                for (int r = 0; r < 16; ++r) {
                    const int kloc = (r & 3) + 8*(r >> 2) + 4*hi;
                    if (kloc > lq) s[r] = -1e30f;
                }
            }
            // ---- online softmax, lane-local (max3-shaped tree) ----
            float a0m = fmaxf(fmaxf(s[0],  s[1]),  s[2]);
            float a1m = fmaxf(fmaxf(s[3],  s[4]),  s[5]);
            float a2m = fmaxf(fmaxf(s[6],  s[7]),  s[8]);
            float a3m = fmaxf(fmaxf(s[9],  s[10]), s[11]);
            float a4m = fmaxf(fmaxf(s[12], s[13]), s[14]);
            float lm  = fmaxf(fmaxf(fmaxf(a0m, a1m), a2m),
                              fmaxf(fmaxf(a3m, a4m), s[15]));
            if (!__all(lm <= mi + 11.5f)) {    // rare rescale path
                float pm = fmaxf(lm, __shfl_xor(lm, 32));
                float mn = fmaxf(mi, pm);
                float sf = fast_exp2(mi - mn);
                si *= sf;
                #pragma unroll
                for (int r = 0; r < 16; ++r) {
                    const int qloc = (r & 3) + 8*(r >> 2) + 4*hi;
                    float sfq = __shfl(sf, qloc);
                    o0[r] *= sfq; o1[r] *= sfq;
                }
                mi = mn;
            }
            float e[16];
            float psum = 0.f;
            #pragma unroll
            for (int r = 0; r < 16; ++r) {
                e[r] = fast_exp2(s[r] - mi);
                psum += e[r];
            }
            si += psum;
            // ---- P A-frags in-register + PV ----
            #pragma unroll
            for (int s2 = 0; s2 < 2; ++s2) {
                unsigned c0 = cvtpk_bf16(e[8*s2 + 0], e[8*s2 + 1]);
                unsigned c1 = cvtpk_bf16(e[8*s2 + 2], e[8*s2 + 3]);
                unsigned c2 = cvtpk_bf16(e[8*s2 + 4], e[8*s2 + 5]);
                unsigned c3 = cvtpk_bf16(e[8*s2 + 6], e[8*s2 + 7]);
                asm("v_permlane32_swap_b32 %0, %1" : "+v"(c0), "+v"(c2));
                asm("v_permlane32_swap_b32 %0, %1" : "+v"(c1), "+v"(c3));
                union { unsigned u[4]; s16x8 v; } pa;
                pa.u[0] = c0; pa.u[1] = c1; pa.u[2] = c2; pa.u[3] = c3;
                const int kc = kti*32 + 16*s2 + 8*hi;
                s16x8 vb0 = *(const s16x8*)&Vs[swz(lq,      kc)];
                s16x8 vb1 = *(const s16x8*)&Vs[swz(32 + lq, kc)];
                __builtin_amdgcn_s_setprio(1);
                o0 = __builtin_amdgcn_mfma_f32_32x32x16_bf16(pa.v, vb0, o0, 0, 0, 0);
                o1 = __builtin_amdgcn_mfma_f32_32x32x16_bf16(pa.v, vb1, o1, 0, 0, 0);
                __builtin_amdgcn_s_setprio(0);
            }
        }
    }
    // ---- epilogue: write UNNORMALIZED partial + (m, s) per q-row ----
    float sfull = si + __shfl_xor(si, 32);
    if (hi == 0) {   // one lane per q-row (mi identical across the two halves)
        const int row = bh * TT + qw0 + lq;
        ms[seg*MS_SEG + row]       = mi;
        ms[(4+seg)*MS_SEG + row]   = sfull;
    }
    unsigned short* op = (seg == 0) ? oA : (seg == 1) ? oB : (seg == 2) ? oC : oD;
    #pragma unroll
    for (int r = 0; r < 16; ++r) {
        const int qloc = (r & 3) + 8*(r >> 2) + 4*hi;
        size_t row = (size_t)(b*TT + qw0 + qloc) * D_MODEL + h*64;
        op[row + lq]      = f2bf(o0[r]);
        op[row + 32 + lq] = f2bf(o1[r]);
    }
}

// ---------------- merge: Y = sum_i oI*2^(mI-m) / sum_i sI*2^(mI-m) ----------
__launch_bounds__(256)
__global__ void merge_kernel(const unsigned short* __restrict__ oA,
                             const unsigned short* __restrict__ oB,
                             const unsigned short* __restrict__ oC,
                             const unsigned short* __restrict__ oD,
                             const float* __restrict__ ms,
                             unsigned short* __restrict__ Yw) {
    const int gid = blockIdx.x * 256 + threadIdx.x;
    const int e = gid * 8;                       // element idx, 8 per thread
    const int t = e / D_MODEL;                   // 0..4095
    const int c = e % D_MODEL;
    const int b = t >> 11, q = t & 2047;
    const int h = c >> 6;
    const int row = (b * N_HEADS + h) * TT + q;
    float m0 = ms[row],            m1 = ms[MS_SEG + row];
    float m2 = ms[2*MS_SEG + row], m3 = ms[3*MS_SEG + row];
    float s0 = ms[4*MS_SEG + row], s1 = ms[5*MS_SEG + row];
    float s2 = ms[6*MS_SEG + row], s3 = ms[7*MS_SEG + row];
    float m  = fmaxf(fmaxf(m0, m1), fmaxf(m2, m3));
    float a0 = fast_exp2(m0 - m), a1 = fast_exp2(m1 - m);
    float a2 = fast_exp2(m2 - m), a3 = fast_exp2(m3 - m);
    float inv = 1.f / (s0*a0 + s1*a1 + s2*a2 + s3*a3);
    float w0 = a0*inv, w1 = a1*inv, w2 = a2*inv, w3 = a3*inv;
    s16x8 va = *(const s16x8*)&oA[e];
    s16x8 vb = *(const s16x8*)&oB[e];
    s16x8 vc = *(const s16x8*)&oC[e];
    s16x8 vd = *(const s16x8*)&oD[e];
    s16x8 out;
    #pragma unroll
    for (int j = 0; j < 8; ++j)
        out[j] = (short)f2bf(bf2f((unsigned short)va[j]) * w0 +
                             bf2f((unsigned short)vb[j]) * w1 +
                             bf2f((unsigned short)vc[j]) * w2 +
                             bf2f((unsigned short)vd[j]) * w3);
    *(s16x8*)&Yw[e] = out;
}

// ---------------- proj GEMM: 32x128 tiles (768 blocks, 3/CU) ----------------
__launch_bounds__(256)
__global__ void proj_kernel(const unsigned short* __restrict__ Y, const unsigned short* __restrict__ Wt,
                            const float* __restrict__ bias, float* __restrict__ Out) {
    __shared__ unsigned short As[32][40];
    __shared__ unsigned short Bs[128][40];
    const int m0 = blockIdx.y * 32;
    const int n0 = blockIdx.x * 128;
    const int tid = threadIdx.x;
    const int l  = tid & 63;
    const int w  = tid >> 6;            // wave -> n-col group w*32
    const int lr = l & 15, lk = (l >> 4) * 8, li = (l >> 4) * 4;

    f32x4 acc[2][2] = {};
    for (int kt = 0; kt < D_MODEL; kt += 32) {
        if (tid < 128) {
            int r = tid >> 2;           // 0..31
            int c = (tid & 3) * 8;
            *(int4*)&As[r][c] = *(const int4*)&Y[(size_t)(m0 + r) * D_MODEL + kt + c];
        }
        #pragma unroll
        for (int p = 0; p < 2; ++p) {
            int ch = tid * 2 + p;
            int r = ch >> 2;
            int c = (ch & 3) * 8;
            *(int4*)&Bs[r][c] = *(const int4*)&Wt[(size_t)(n0 + r) * D_MODEL + kt + c];
        }
        __syncthreads();
        s16x8 a[2], bf[2];
        a[0] = *(const s16x8*)&As[lr][lk];
        a[1] = *(const s16x8*)&As[16 + lr][lk];
        bf[0] = *(const s16x8*)&Bs[w*32 + lr][lk];
        bf[1] = *(const s16x8*)&Bs[w*32 + 16 + lr][lk];
        #pragma unroll
        for (int mi2 = 0; mi2 < 2; ++mi2)
            #pragma unroll
            for (int ni = 0; ni < 2; ++ni)
                acc[mi2][ni] = __builtin_amdgcn_mfma_f32_16x16x32_bf16(a[mi2], bf[ni], acc[mi2][ni], 0, 0, 0);
        __syncthreads();
    }
    #pragma unroll
    for (int ni = 0; ni < 2; ++ni) {
        int ng = n0 + w*32 + ni*16 + lr;
        float bv = bias[ng];
        #pragma unroll
        for (int mi2 = 0; mi2 < 2; ++mi2)
            #pragma unroll
            for (int i = 0; i < 4; ++i) {
                int t = m0 + mi2*16 + li + i;
                Out[(size_t)t * D_MODEL + ng] = acc[mi2][ni][i] + bv;
            }
    }
}

extern "C" void kernel_launch(void* const* d_in, const int* in_sizes, int n_in,
                              void* d_out, int out_size, void* d_ws, size_t ws_size,
                              hipStream_t stream) {
    const float* x      = (const float*)d_in[0];
    const float* w_attn = (const float*)d_in[1];
    const float* b_attn = (const float*)d_in[2];
    const float* w_proj = (const float*)d_in[3];
    const float* b_proj = (const float*)d_in[4];
    float* out = (float*)d_out;

    unsigned short* wt_attn = (unsigned short*)d_ws;                       // 2304*768
    unsigned short* wt_proj = wt_attn + (size_t)N_QKV * D_MODEL;           // 768*768
    unsigned short* Qw      = wt_proj + (size_t)D_MODEL * D_MODEL;
    unsigned short* Kw      = Qw + (size_t)M_TOK * D_MODEL;
    unsigned short* Vw      = Kw + (size_t)M_TOK * D_MODEL;
    unsigned short* Yw      = Vw + (size_t)M_TOK * D_MODEL;
    unsigned short* Xb      = Yw + (size_t)M_TOK * D_MODEL;
    unsigned short* oC      = Xb + (size_t)M_TOK * D_MODEL;
    unsigned short* oD      = oC + (size_t)M_TOK * D_MODEL;
    unsigned short* Vtw     = Xb;              // Xb dead after qkv; reuse for V^T
    unsigned short* oA      = Vw;              // Vw dead after vtrans: seg0 partial
    unsigned short* oB      = Yw;              // seg1 partial, merged in place
    float*          msbuf   = (float*)d_ws;    // wt_attn region dead after qkv

    hipLaunchKernelGGL(prep_kernel, dim3(1536 + 72*24 + 24*24), dim3(256), 0, stream,
                       x, Xb, w_attn, w_proj, wt_attn, wt_proj);
    hipLaunchKernelGGL(qkv_kernel, dim3(N_QKV/128, M_TOK/128), dim3(256), 0, stream,
                       Xb, wt_attn, b_attn, Qw, Kw, Vw);
    hipLaunchKernelGGL(vtrans_kernel, dim3(TT/64, BB*N_HEADS), dim3(256), 0, stream,
                       Vw, Vtw);
    hipLaunchKernelGGL(attn_kernel, dim3(64, BB*N_HEADS), dim3(256), 0, stream,
                       Qw, Kw, Vtw, oA, oB, oC, oD, msbuf);
    hipLaunchKernelGGL(merge_kernel, dim3(M_TOK*D_MODEL/8/256), dim3(256), 0, stream,
                       oA, oB, oC, oD, msbuf, Yw);
    hipLaunchKernelGGL(proj_kernel, dim3(D_MODEL/128, M_TOK/32), dim3(256), 0, stream,
                       Yw, wt_proj, b_proj, out);
}